// Round 1
// baseline (124.393 us; speedup 1.0000x reference)
//
#include <hip/hip_runtime.h>

// CostVolume: x,y fp32 [2,64,96,320]; GROUP=8 -> 8 groups x 8 channels.
// Per group: L2-normalize the 8-channel vector per pixel (+EPS on the norm),
// cost[b,g,d,h,j] = sum_cc | xn[cc][h][j] - yn[cc][h][j-d] |, with yn term = 0
// when j < d (left zero-pad). Output [2,8,49,96,320] fp32.
//
// One block per (b,g,h) row: 320 threads (5 waves), thread j owns column j.
// xn kept in registers; yn staged in LDS as two float4 rows -> conflict-free
// ds_read_b128 at lane stride 16B. For j<d, cost == sum|xn| (precomputed).

#define MAXDISP 48
#define NDISP   49
#define HH      96
#define WW      320
#define EPSN    1e-5f

__global__ __launch_bounds__(WW) void cost_volume_kernel(
    const float* __restrict__ x, const float* __restrict__ y,
    float* __restrict__ out)
{
    __shared__ float4 ylds[2 * WW];   // [half][j] : half0 = ch0..3, half1 = ch4..7

    const int j   = threadIdx.x;      // 0..319
    const int blk = blockIdx.x;       // 0..1535
    const int h   = blk % HH;
    const int bg  = blk / HH;         // b*8 + g, 0..15

    // input flat idx = ((b*64 + g*8 + cc)*96 + h)*320 + j
    //                = (bg*8 + cc)*30720 + h*320 + j
    const int inBase = bg * 8 * (HH * WW) + h * WW + j;

    float xv[8], yv[8];
    float xs = 0.f, ys = 0.f;
#pragma unroll
    for (int cc = 0; cc < 8; ++cc) {
        float xi = x[inBase + cc * (HH * WW)];
        float yi = y[inBase + cc * (HH * WW)];
        xv[cc] = xi; yv[cc] = yi;
        xs += xi * xi;
        ys += yi * yi;
    }
    const float xinv = 1.f / (sqrtf(xs) + EPSN);
    const float yinv = 1.f / (sqrtf(ys) + EPSN);

    float sAbs = 0.f;
#pragma unroll
    for (int cc = 0; cc < 8; ++cc) {
        xv[cc] *= xinv;
        yv[cc] *= yinv;
        sAbs += fabsf(xv[cc]);
    }

    ylds[j]      = make_float4(yv[0], yv[1], yv[2], yv[3]);
    ylds[WW + j] = make_float4(yv[4], yv[5], yv[6], yv[7]);
    __syncthreads();

    // out flat idx = ((bg*49 + d)*96 + h)*320 + j
    float* outp = out + bg * (NDISP * HH * WW) + h * WW + j;

#pragma unroll 7
    for (int d = 0; d < NDISP; ++d) {
        float cost;
        const int jj = j - d;
        if (jj >= 0) {
            const float4 a = ylds[jj];
            const float4 b = ylds[WW + jj];
            cost = fabsf(xv[0] - a.x) + fabsf(xv[1] - a.y)
                 + fabsf(xv[2] - a.z) + fabsf(xv[3] - a.w)
                 + fabsf(xv[4] - b.x) + fabsf(xv[5] - b.y)
                 + fabsf(xv[6] - b.z) + fabsf(xv[7] - b.w);
        } else {
            cost = sAbs;   // shifted y is the zero pad: |xn - 0| summed
        }
        outp[d * (HH * WW)] = cost;
    }
}

extern "C" void kernel_launch(void* const* d_in, const int* in_sizes, int n_in,
                              void* d_out, int out_size, void* d_ws, size_t ws_size,
                              hipStream_t stream) {
    const float* x = (const float*)d_in[0];
    const float* y = (const float*)d_in[1];
    float* out = (float*)d_out;
    // grid = B * GROUP * H = 2*8*96 = 1536 blocks, one per (b,g,h) row
    dim3 grid(2 * 8 * HH);
    dim3 block(WW);
    cost_volume_kernel<<<grid, block, 0, stream>>>(x, y, out);
}